// Round 1
// baseline (493.664 us; speedup 1.0000x reference)
//
#include <hip/hip_runtime.h>
#include <hip/hip_bf16.h>
#include <stdint.h>

#define NROWS 8192   // N
#define KDIM  512    // IN_F
#define NOUT  512    // OUT_F
#define KADJ  8192   // K of the aggregation GEMM

using bf16x8   = __attribute__((ext_vector_type(8))) __bf16;
using f32x4    = __attribute__((ext_vector_type(4))) float;
using short4_t = __attribute__((ext_vector_type(4))) short;

__device__ __forceinline__ short f2bf(float f) {
    return (short)__bfloat16_as_ushort(__float2bfloat16(f));
}

__device__ __forceinline__ void gld_lds16(const void* g, void* l) {
    __builtin_amdgcn_global_load_lds(
        (const __attribute__((address_space(1))) void*)g,
        (__attribute__((address_space(3))) void*)l, 16, 0, 0);
}

// ---------------- Stage 1: ht[n][m] = (input @ W^T + b)^T in bf16 ----------------
// GEMM: M'=NOUT rows (n, from W), N'=NROWS cols (m, from input), K=KDIM.
// Tile 64(n) x 128(m), BK=64. 4 waves, each 64n x 32m. Grid = 8 * 64 = 512.
__global__ __launch_bounds__(256)
void linear_ht_kernel(const float* __restrict__ input,
                      const float* __restrict__ W,
                      const float* __restrict__ bias,
                      short* __restrict__ ht)
{
    __shared__ short Ws[64 * 64];    // [n][k] bf16, XOR-swizzled, 8 KB
    __shared__ short Is[128 * 64];   // [m][k] bf16, XOR-swizzled, 16 KB

    const int bid  = blockIdx.x;
    const int nblk = bid & 7;        // 8 tiles of 64 over NOUT
    const int mblk = bid >> 3;       // 64 tiles of 128 over NROWS
    const int tid  = threadIdx.x;
    const int w    = tid >> 6;
    const int l    = tid & 63;
    const int wm   = w;              // wave's 32-wide m strip
    const int lr   = l >> 4, lc = l & 15;

    f32x4 acc[4][2];
    #pragma unroll
    for (int a = 0; a < 4; ++a)
        #pragma unroll
        for (int c = 0; c < 2; ++c) acc[a][c] = (f32x4){0.f, 0.f, 0.f, 0.f};

    const int srow = tid >> 4;           // staging row base (+16 per iter)
    const int scw  = (tid & 15) * 4;     // float col
    const int swz  = (srow & 7) << 4;    // row-XOR (low 3 bits invariant under +16)

    for (int kt = 0; kt < KDIM / 64; ++kt) {
        const int k0 = kt * 64;
        // stage W tile 64x64 (fp32 -> bf16, swizzled)
        #pragma unroll
        for (int i = 0; i < 4; ++i) {
            int r = srow + i * 16;
            float4 v = *reinterpret_cast<const float4*>(
                W + (size_t)(nblk * 64 + r) * KDIM + k0 + scw);
            short4_t s4 = { f2bf(v.x), f2bf(v.y), f2bf(v.z), f2bf(v.w) };
            int off = r * 128 + ((scw * 2) ^ swz);
            *reinterpret_cast<short4_t*>((char*)Ws + off) = s4;
        }
        // stage input tile 128x64
        #pragma unroll
        for (int i = 0; i < 8; ++i) {
            int r = srow + i * 16;
            float4 v = *reinterpret_cast<const float4*>(
                input + (size_t)(mblk * 128 + r) * KDIM + k0 + scw);
            short4_t s4 = { f2bf(v.x), f2bf(v.y), f2bf(v.z), f2bf(v.w) };
            int off = r * 128 + ((scw * 2) ^ swz);
            *reinterpret_cast<short4_t*>((char*)Is + off) = s4;
        }
        __syncthreads();
        const int kq = lr * 8;
        #pragma unroll
        for (int kk = 0; kk < 2; ++kk) {
            const int lbk = (kk * 32 + kq) * 2;
            bf16x8 af[4], bfr[2];
            #pragma unroll
            for (int fm = 0; fm < 4; ++fm) {
                int r = fm * 16 + lc;
                af[fm] = *reinterpret_cast<const bf16x8*>(
                    (char*)Ws + r * 128 + (lbk ^ ((r & 7) << 4)));
            }
            #pragma unroll
            for (int fb = 0; fb < 2; ++fb) {
                int r = wm * 32 + fb * 16 + lc;
                bfr[fb] = *reinterpret_cast<const bf16x8*>(
                    (char*)Is + r * 128 + (lbk ^ ((r & 7) << 4)));
            }
            #pragma unroll
            for (int fm = 0; fm < 4; ++fm)
                #pragma unroll
                for (int fb = 0; fb < 2; ++fb)
                    acc[fm][fb] = __builtin_amdgcn_mfma_f32_16x16x32_bf16(
                        af[fm], bfr[fb], acc[fm][fb], 0, 0, 0);
        }
        __syncthreads();
    }
    // epilogue: ht[n][m] = acc + bias[n]  (bf16, transposed store)
    #pragma unroll
    for (int fm = 0; fm < 4; ++fm)
        #pragma unroll
        for (int fb = 0; fb < 2; ++fb)
            #pragma unroll
            for (int j = 0; j < 4; ++j) {
                int n = nblk * 64 + fm * 16 + lr * 4 + j;
                int m = mblk * 128 + wm * 32 + fb * 16 + lc;
                ht[(size_t)n * NROWS + m] = f2bf(acc[fm][fb][j] + bias[n]);
            }
}

// ---------------- Stage 2: out += adj @ h ----------------
// M=8192, N=512, K=8192. Tile 128x128, BK=64, split-K=2.
// Grid = 64(row) * 4(col) * 2(kchunk) = 512. 4 waves 2x2, 64x64 each.
__global__ __launch_bounds__(256)
void agg_kernel(const float* __restrict__ adj,
                const short* __restrict__ ht,
                float* __restrict__ out)
{
    __shared__ short As[128 * 64];   // adj tile bf16, swizzled
    __shared__ short Bs[128 * 64];   // ht tile bf16, swizzled content (linear gld_lds dest)

    const int bid  = blockIdx.x;
    const int kc   = bid >> 8;       // 0..1
    const int rem  = bid & 255;
    const int brow = rem >> 2;       // 0..63  (col-fast => 4 sharers of adj panel adjacent)
    const int bcol = rem & 3;        // 0..3
    const int tid  = threadIdx.x;
    const int w    = tid >> 6;
    const int l    = tid & 63;
    const int wr   = w >> 1, wc = w & 1;
    const int lr   = l >> 4, lc = l & 15;

    f32x4 acc[4][4];
    #pragma unroll
    for (int a = 0; a < 4; ++a)
        #pragma unroll
        for (int c = 0; c < 4; ++c) acc[a][c] = (f32x4){0.f, 0.f, 0.f, 0.f};

    const int srow = tid >> 4;
    const int scw  = (tid & 15) * 4;
    const int swz  = (srow & 7) << 4;

    // B staging: linear LDS dest, pre-swizzled global source (involution ^)
    const int br_off = l >> 3;                       // row within 8-row segment
    const int bcl    = ((l & 7) ^ ((l >> 3) & 7)) * 8; // bf16 element offset (16B chunk)

    for (int kt = 0; kt < 64; ++kt) {
        const int k0 = kc * 4096 + kt * 64;
        // stage A: adj fp32 -> bf16, swizzled ds_write
        #pragma unroll
        for (int i = 0; i < 8; ++i) {
            int r = srow + i * 16;
            float4 v = *reinterpret_cast<const float4*>(
                adj + (size_t)(brow * 128 + r) * KADJ + k0 + scw);
            short4_t s4 = { f2bf(v.x), f2bf(v.y), f2bf(v.z), f2bf(v.w) };
            int off = r * 128 + ((scw * 2) ^ swz);
            *reinterpret_cast<short4_t*>((char*)As + off) = s4;
        }
        // stage B: ht bf16 via global_load_lds (16B), source pre-swizzled
        #pragma unroll
        for (int j = 0; j < 4; ++j) {
            int s = w * 4 + j;
            int r = s * 8 + br_off;
            gld_lds16(ht + (size_t)(bcol * 128 + r) * KADJ + k0 + bcl,
                      (char*)Bs + s * 1024);
        }
        __syncthreads();
        const int kq = lr * 8;
        #pragma unroll
        for (int kk = 0; kk < 2; ++kk) {
            const int lbk = (kk * 32 + kq) * 2;
            bf16x8 af[4], bfr[4];
            #pragma unroll
            for (int fm = 0; fm < 4; ++fm) {
                int r = wr * 64 + fm * 16 + lc;
                af[fm] = *reinterpret_cast<const bf16x8*>(
                    (char*)As + r * 128 + (lbk ^ ((r & 7) << 4)));
            }
            #pragma unroll
            for (int fn = 0; fn < 4; ++fn) {
                int r = wc * 64 + fn * 16 + lc;
                bfr[fn] = *reinterpret_cast<const bf16x8*>(
                    (char*)Bs + r * 128 + (lbk ^ ((r & 7) << 4)));
            }
            #pragma unroll
            for (int fm = 0; fm < 4; ++fm)
                #pragma unroll
                for (int fn = 0; fn < 4; ++fn)
                    acc[fm][fn] = __builtin_amdgcn_mfma_f32_16x16x32_bf16(
                        af[fm], bfr[fn], acc[fm][fn], 0, 0, 0);
        }
        __syncthreads();
    }
    // epilogue: split-K partial -> fp32 atomics onto zeroed out
    #pragma unroll
    for (int fm = 0; fm < 4; ++fm)
        #pragma unroll
        for (int fn = 0; fn < 4; ++fn) {
            int row0 = brow * 128 + wr * 64 + fm * 16 + lr * 4;
            int col  = bcol * 128 + wc * 64 + fn * 16 + lc;
            #pragma unroll
            for (int j = 0; j < 4; ++j)
                atomicAdd(&out[(size_t)(row0 + j) * NOUT + col], acc[fm][fn][j]);
        }
}

extern "C" void kernel_launch(void* const* d_in, const int* in_sizes, int n_in,
                              void* d_out, int out_size, void* d_ws, size_t ws_size,
                              hipStream_t stream) {
    const float* input = (const float*)d_in[0];   // [8192, 512]
    const float* adj   = (const float*)d_in[1];   // [8192, 8192]
    const float* W     = (const float*)d_in[2];   // [512, 512]
    const float* bias  = (const float*)d_in[3];   // [512]
    float* out = (float*)d_out;                   // [8192, 512] fp32
    short* ht  = (short*)d_ws;                    // [512][8192] bf16, 8 MB

    // zero output (split-K accumulates atomically); graph-capture-safe stream op
    hipMemsetAsync(d_out, 0, (size_t)out_size * sizeof(float), stream);

    linear_ht_kernel<<<512, 256, 0, stream>>>(input, W, bias, ht);
    agg_kernel<<<512, 256, 0, stream>>>(adj, ht, out);
}